// Round 4
// baseline (585.376 us; speedup 1.0000x reference)
//
#include <hip/hip_runtime.h>

#define B   64
#define KK  4096
#define D   256
#define Q   8
#define H   4
#define DH  64
#define HQ  32
#define HM  512
#define NCH 16
#define CHK 256
#define EPS 1e-8f
#define LNE 1e-5f
#define SCALE 0.125f

typedef short bf16x8 __attribute__((ext_vector_type(8)));
typedef float f32x4 __attribute__((ext_vector_type(4)));

#define MFMA __builtin_amdgcn_mfma_f32_16x16x32_bf16

__device__ __forceinline__ float bf2f(unsigned short u) {
    unsigned int x = ((unsigned int)u) << 16;
    float f; __builtin_memcpy(&f, &x, 4); return f;
}
__device__ __forceinline__ unsigned short f2bf(float f) {
    unsigned int x; __builtin_memcpy(&x, &f, 4);
    unsigned int lsb = (x >> 16) & 1u;
    x += 0x7fffu + lsb;
    return (unsigned short)(x >> 16);
}

__device__ __forceinline__ void gload16(const void* g, void* l) {
    __builtin_amdgcn_global_load_lds(
        (const __attribute__((address_space(1))) unsigned int*)g,
        (__attribute__((address_space(3))) unsigned int*)l, 16, 0, 0);
}

// ---------------- prep kernels ----------------
__global__ void k_init(const float* __restrict__ s0, float* __restrict__ slots)
{
    const int i = blockIdx.x * 256 + threadIdx.x;
    slots[i] = s0[i];
}

__global__ __launch_bounds__(256) void k0_wkv(
    const float* __restrict__ Wk, const float* __restrict__ Wv,
    unsigned short* __restrict__ WkvT)
{
    const int c = blockIdx.x, d = threadIdx.x;
    const float v = (c < 256) ? Wk[(size_t)d * 256 + c] * SCALE
                              : Wv[(size_t)d * 256 + (c - 256)];
    WkvT[(size_t)c * 256 + d] = f2bf(v);
}

__global__ void k0_cvt(const float* __restrict__ src, unsigned short* __restrict__ dst)
{
    const int i = blockIdx.x * 256 + threadIdx.x;
    dst[i] = f2bf(src[i]);
}

__global__ void k0_t1(const float* __restrict__ W1, unsigned short* __restrict__ W1T)
{   // [256][512] -> bf16 [512][256]
    const int nn = blockIdx.x, d = threadIdx.x;
    W1T[(size_t)nn * 256 + d] = f2bf(W1[(size_t)d * 512 + nn]);
}

__global__ void k0_t2(const float* __restrict__ W2, unsigned short* __restrict__ W2T)
{   // [512][256] -> bf16 [256][512]
    const int nn = blockIdx.x, j = threadIdx.x;
    W2T[(size_t)nn * 512 + j]       = f2bf(W2[(size_t)j * 256 + nn]);
    W2T[(size_t)nn * 512 + 256 + j] = f2bf(W2[(size_t)(256 + j) * 256 + nn]);
}

__global__ void k0_wq(const float* __restrict__ Wq, unsigned short* __restrict__ WqT)
{   // [256][256] -> bf16 [n][k]
    const int nn = blockIdx.x, d = threadIdx.x;
    WqT[(size_t)nn * 256 + d] = f2bf(Wq[(size_t)d * 256 + nn]);
}

// ---------------- K1: LN + K/V projection (MFMA, 48KB LDS, 3 blk/CU) ------
__global__ __launch_bounds__(256) void k1_mfma(
    const float* __restrict__ inp, const unsigned short* __restrict__ WkvT,
    const float* __restrict__ lnw, const float* __restrict__ lnb,
    unsigned short* __restrict__ kbuf, unsigned short* __restrict__ vbufT)
{
    __shared__ char smem[49152];
    char* abase = smem;            // 32KB A (dead after hoist)
    char* bb0 = smem + 32768;      // 16KB B buf0
    char* bb1 = smem;              // 16KB B buf1 (aliases A)
    const int t = threadIdx.x, w = t >> 6, l = t & 63;
    const size_t row0 = (size_t)blockIdx.x * 64;

    auto stageB = [&](int n2, char* dst) {   // 32 WkvT cols (rows of [c][k]) -> 16KB
#pragma unroll
        for (int i = 0; i < 4; ++i) {
            const int seg = w * 4 + i;
            const int r = seg * 2 + (l >> 5);
            const int off = ((l & 31) * 16) ^ ((r & 7) << 4);
            gload16((const char*)WkvT + ((size_t)n2 * 32 + r) * 512 + off, dst + seg * 1024);
        }
    };
    stageB(0, bb0);

    // LN rows -> bf16 swizzled LDS
    float4 xv[16];
#pragma unroll
    for (int i = 0; i < 16; ++i)
        xv[i] = ((const float4*)(inp + (row0 + w * 16 + i) * D))[l];
    const float4 w4 = ((const float4*)lnw)[l];
    const float4 b4 = ((const float4*)lnb)[l];
#pragma unroll
    for (int i = 0; i < 16; ++i) {
        const int r = w * 16 + i;
        float4 x = xv[i];
        float s  = x.x + x.y + x.z + x.w;
        float ss = x.x*x.x + x.y*x.y + x.z*x.z + x.w*x.w;
#pragma unroll
        for (int off = 32; off; off >>= 1) { s += __shfl_xor(s, off); ss += __shfl_xor(ss, off); }
        const float mu = s * (1.f / 256.f);
        const float rs = rsqrtf(ss * (1.f / 256.f) - mu * mu + LNE);
        ushort4 pk;
        pk.x = f2bf((x.x - mu) * rs * w4.x + b4.x);
        pk.y = f2bf((x.y - mu) * rs * w4.y + b4.y);
        pk.z = f2bf((x.z - mu) * rs * w4.z + b4.z);
        pk.w = f2bf((x.w - mu) * rs * w4.w + b4.w);
        *(ushort4*)(abase + r * 512 + ((l * 8) ^ ((r & 7) << 4))) = pk;
    }
    __syncthreads();                        // A ready, B0 landed

    const int arow = w * 16 + (l & 15);
    const char* ap = abase + arow * 512;
    const int asw = (l & 7) << 4;
    bf16x8 af[8];
#pragma unroll
    for (int kk = 0; kk < 8; ++kk)
        af[kk] = *(const bf16x8*)(ap + ((kk * 64 + (l >> 4) * 16) ^ asw));
    __syncthreads();                        // hoists done; A region dead
    stageB(1, bb1);

    const f32x4 fz = {0.f, 0.f, 0.f, 0.f};
    for (int n2 = 0; n2 < 16; ++n2) {
        const char* bbase = (n2 & 1) ? bb1 : bb0;
        f32x4 acc[2] = {fz, fz};
#pragma unroll
        for (int kk = 0; kk < 8; ++kk) {
            const int koff = kk * 64 + (l >> 4) * 16;
#pragma unroll
            for (int nf = 0; nf < 2; ++nf) {
                const int brow = nf * 16 + (l & 15);
                const bf16x8 bf_ = *(const bf16x8*)(bbase + brow * 512 + (koff ^ ((brow & 7) << 4)));
                acc[nf] = MFMA(af[kk], bf_, acc[nf], 0, 0, 0);
            }
        }
        const int c0 = n2 * 32;
        const size_t grow0 = row0 + w * 16 + (l >> 4) * 4;
#pragma unroll
        for (int nf = 0; nf < 2; ++nf) {
            const int c = c0 + nf * 16 + (l & 15);
            if (c < 256) {
#pragma unroll
                for (int reg = 0; reg < 4; ++reg)
                    kbuf[(grow0 + reg) * 256 + c] = f2bf(acc[nf][reg]);
            } else {
                const int cc = c - 256;
                const size_t bb = grow0 >> 12;
                const int kl = (int)(grow0 & 4095);
                ushort4 pk;
                pk.x = f2bf(acc[nf][0]); pk.y = f2bf(acc[nf][1]);
                pk.z = f2bf(acc[nf][2]); pk.w = f2bf(acc[nf][3]);
                *(ushort4*)(vbufT + ((bb * 256 + cc) * KK + kl)) = pk;
            }
        }
        __syncthreads();                    // reads of buf[n2&1] done; stage(n2+1) landed
        if (n2 < 14) stageB(n2 + 2, (n2 & 1) ? bb1 : bb0);
    }
}

// ---------------- K2: LN(slots) + q projection (iter 0 only) ----------------
__global__ __launch_bounds__(256) void k2_qproj(
    const float* __restrict__ slots, const float* __restrict__ Wq,
    const float* __restrict__ lnw, const float* __restrict__ lnb, float* __restrict__ qbuf)
{
    const int row = blockIdx.x, t = threadIdx.x;
    __shared__ float sn[256];
    __shared__ float red[8];
    const float x = slots[(size_t)row * D + t];
    float mu, rs;
    {
        float s = x, ss = x * x;
#pragma unroll
        for (int off = 32; off; off >>= 1) { s += __shfl_xor(s, off); ss += __shfl_xor(ss, off); }
        if ((t & 63) == 0) { red[t >> 6] = s; red[4 + (t >> 6)] = ss; }
        __syncthreads();
        const float S  = red[0] + red[1] + red[2] + red[3];
        const float SS = red[4] + red[5] + red[6] + red[7];
        mu = S * (1.f / 256.f);
        rs = rsqrtf(SS * (1.f / 256.f) - mu * mu + LNE);
    }
    sn[t] = (x - mu) * rs * lnw[t] + lnb[t];
    __syncthreads();
    float acc = 0.f;
    for (int d = 0; d < 256; ++d) acc = fmaf(sn[d], Wq[(size_t)d * 256 + t], acc);
    qbuf[(size_t)row * D + t] = acc;
}

// ---------------- fused attention: logits + joint softmax + PV --------------
// grid = B*NCH; per block: 256 k-rows in 4 tiles of 64. K/V direct to VGPR.
__global__ __launch_bounds__(256) void k_attn(
    const unsigned short* __restrict__ kbuf, const unsigned short* __restrict__ vbufT,
    const float* __restrict__ qbuf, float* __restrict__ updp,
    float* __restrict__ denp, float* __restrict__ pbuf, int write_p)
{
    __shared__ unsigned short psm[32 * 64];    // P^T [32 hq][64 k], swizzled
    __shared__ float dred[4][32];
    const int t = threadIdx.x, w = t >> 6, l = t & 63;
    const int b = blockIdx.x >> 4, chunk = blockIdx.x & 15;
    const int k0g = chunk * CHK;
    const int n = l & 15, lg = l >> 4;

    // q fragments (block-diagonal Q32)
    bf16x8 qf[2][2];
#pragma unroll
    for (int p = 0; p < 2; ++p) {
        const int h = p * 2 + (n >> 3);
        const float* qb = qbuf + ((size_t)b * Q + (n & 7)) * D;
#pragma unroll
        for (int j = 0; j < 2; ++j) {
            const int dbase = (h * 2 + j) * 32 + lg * 8;
            short tmp[8];
#pragma unroll
            for (int e = 0; e < 8; ++e) tmp[e] = (short)f2bf(qb[dbase + e]);
            __builtin_memcpy(&qf[p][j], tmp, 16);
        }
    }
    const bf16x8 ZV = {0,0,0,0,0,0,0,0};
    const f32x4 fz = {0.f,0.f,0.f,0.f};
    f32x4 pv[2][4];
#pragma unroll
    for (int mt = 0; mt < 2; ++mt)
#pragma unroll
        for (int nf = 0; nf < 4; ++nf) pv[mt][nf] = fz;
    float den0 = 0.f, den1 = 0.f;

    const unsigned short* kbase = kbuf + ((size_t)b * KK + k0g + w * 16 + n) * 256 + lg * 8;

    for (int tile = 0; tile < 4; ++tile) {
        // K frags direct from global (row-major == fragment layout)
        bf16x8 kf[8];
#pragma unroll
        for (int kk = 0; kk < 8; ++kk)
            kf[kk] = *(const bf16x8*)(kbase + (size_t)tile * 64 * 256 + kk * 32);
        f32x4 lac[2] = {fz, fz};
#pragma unroll
        for (int kk = 0; kk < 8; ++kk) {
            const int p = kk >> 2;
            const bool on = (((kk & 3) >> 1) == (n >> 3));
            const bf16x8 bq = on ? qf[p][kk & 1] : ZV;
            if (p == 0) lac[0] = MFMA(kf[kk], bq, lac[0], 0, 0, 0);
            else        lac[1] = MFMA(kf[kk], bq, lac[1], 0, 0, 0);
        }
        // joint softmax over 32 (h,q) per k-row (row spread over 16 lanes)
#pragma unroll
        for (int reg = 0; reg < 4; ++reg) {
            float m = fmaxf(lac[0][reg], lac[1][reg]);
#pragma unroll
            for (int off = 8; off; off >>= 1) m = fmaxf(m, __shfl_xor(m, off));
            const float e0 = __expf(lac[0][reg] - m);
            const float e1 = __expf(lac[1][reg] - m);
            float se = e0 + e1;
#pragma unroll
            for (int off = 8; off; off >>= 1) se += __shfl_xor(se, off);
            const float inv = 1.f / se;
            lac[0][reg] = e0 * inv; lac[1][reg] = e1 * inv;
            den0 += lac[0][reg];    den1 += lac[1][reg];
        }
        __syncthreads();     // all waves done reading psm (previous tile PV)
        const int kb = w * 16 + lg * 4;
        {
            ushort4 p0, p1;
            p0.x = f2bf(lac[0][0]); p0.y = f2bf(lac[0][1]); p0.z = f2bf(lac[0][2]); p0.w = f2bf(lac[0][3]);
            p1.x = f2bf(lac[1][0]); p1.y = f2bf(lac[1][1]); p1.z = f2bf(lac[1][2]); p1.w = f2bf(lac[1][3]);
            *(ushort4*)((char*)psm + n * 128 + ((kb * 2) ^ ((n & 7) << 4))) = p0;
            *(ushort4*)((char*)psm + (16 + n) * 128 + ((kb * 2) ^ ((n & 7) << 4))) = p1;
        }
        if (write_p) {
            float* pp = pbuf + ((size_t)b * KK + k0g + tile * 64 + kb) * HQ;
#pragma unroll
            for (int reg = 0; reg < 4; ++reg) {
                pp[(size_t)reg * HQ + n] = lac[0][reg];
                pp[(size_t)reg * HQ + 16 + n] = lac[1][reg];
            }
        }
        __syncthreads();     // psm ready
        // PV: V frags direct from global
#pragma unroll
        for (int kkp = 0; kkp < 2; ++kkp) {
            const int koff = kkp * 64 + lg * 16;
            const bf16x8 a0 = *(const bf16x8*)((char*)psm + n * 128 + (koff ^ ((n & 7) << 4)));
            const bf16x8 a1 = *(const bf16x8*)((char*)psm + (16 + n) * 128 + (koff ^ ((n & 7) << 4)));
#pragma unroll
            for (int nf = 0; nf < 4; ++nf) {
                const int d = w * 64 + nf * 16 + n;
                const bf16x8 bv = *(const bf16x8*)(vbufT + ((size_t)b * 256 + d) * KK
                                                   + k0g + tile * 64 + kkp * 32 + lg * 8);
                pv[0][nf] = MFMA(a0, bv, pv[0][nf], 0, 0, 0);
                pv[1][nf] = MFMA(a1, bv, pv[1][nf], 0, 0, 0);
            }
        }
    }

    den0 += __shfl_xor(den0, 16); den0 += __shfl_xor(den0, 32);
    den1 += __shfl_xor(den1, 16); den1 += __shfl_xor(den1, 32);
    if (l < 16) { dred[w][l] = den0; dred[w][16 + l] = den1; }
    __syncthreads();
    if (t < 32)
        denp[((size_t)b * NCH + chunk) * HQ + t] =
            dred[0][t] + dred[1][t] + dred[2][t] + dred[3][t];

    if ((lg >> 1) == (w & 1)) {
        const int mt = w >> 1;
#pragma unroll
        for (int nf = 0; nf < 4; ++nf) {
#pragma unroll
            for (int reg = 0; reg < 4; ++reg) {
                const int q = (lg & 1) * 4 + reg;
                updp[(((size_t)b * NCH + chunk) * Q + q) * D + w * 64 + nf * 16 + n] = pv[mt][nf][reg];
            }
        }
    }
}

// ---------------- LN helper for k_slot (per-row over C-fragment layout) -----
__device__ __forceinline__ void ln_rows(const f32x4 sv[4], char* dstA, float* red,
    const float* __restrict__ lnw, const float* __restrict__ lnb,
    int w, int n, int lg, int col0)
{
    float ps[4], pq[4];
#pragma unroll
    for (int r = 0; r < 4; ++r) {
        float s = 0.f, q2 = 0.f;
#pragma unroll
        for (int nf = 0; nf < 4; ++nf) { const float v = sv[nf][r]; s += v; q2 += v * v; }
#pragma unroll
        for (int off = 1; off < 16; off <<= 1) { s += __shfl_xor(s, off); q2 += __shfl_xor(q2, off); }
        ps[r] = s; pq[r] = q2;
    }
    if (n == 0) {
#pragma unroll
        for (int r = 0; r < 4; ++r) {
            red[(lg * 4 + r) * 8 + w * 2]     = ps[r];
            red[(lg * 4 + r) * 8 + w * 2 + 1] = pq[r];
        }
    }
    __syncthreads();
    float mu[4], rs[4];
#pragma unroll
    for (int r = 0; r < 4; ++r) {
        const int rowm = lg * 4 + r;
        const float S  = red[rowm*8+0] + red[rowm*8+2] + red[rowm*8+4] + red[rowm*8+6];
        const float SS = red[rowm*8+1] + red[rowm*8+3] + red[rowm*8+5] + red[rowm*8+7];
        mu[r] = S * (1.f / 256.f);
        rs[r] = rsqrtf(SS * (1.f / 256.f) - mu[r] * mu[r] + LNE);
    }
#pragma unroll
    for (int nf = 0; nf < 4; ++nf) {
        const int col = col0 + nf * 16;
        const float wv = lnw[col], bv = lnb[col];
#pragma unroll
        for (int r = 0; r < 4; ++r) {
            const int rowm = lg * 4 + r;
            const float mval = (sv[nf][r] - mu[r]) * rs[r] * wv + bv;
            *(unsigned short*)(dstA + rowm * 512 + ((col * 2) ^ ((rowm & 7) << 4))) = f2bf(mval);
        }
    }
}

// ---------------- fused slot update: reduce+GRU+LN+MLP+LN+qproj -------------
// grid = 32 blocks x 16 rows. Weights ([n][k] bf16) read direct from L2.
__global__ __launch_bounds__(256) void k_slot(
    const float* __restrict__ updp, const float* __restrict__ denp,
    float* __restrict__ slots,
    const unsigned short* __restrict__ Wihbf, const unsigned short* __restrict__ Whhbf,
    const float* __restrict__ bih, const float* __restrict__ bhh,
    const unsigned short* __restrict__ W1T, const float* __restrict__ b1,
    const unsigned short* __restrict__ W2T, const float* __restrict__ b2,
    const float* __restrict__ lnmw, const float* __restrict__ lnmb,
    const unsigned short* __restrict__ WqT,
    const float* __restrict__ lnsw, const float* __restrict__ lnsb,
    float* __restrict__ qbuf)
{
    __shared__ char sm[34304];
    unsigned short* uA = (unsigned short*)(sm);          // [16] rows x 512B swz (alias: mA)
    unsigned short* hA = (unsigned short*)(sm + 8192);   // (alias: mqA)
    float* hf32        = (float*)(sm + 16384);           // [16][264] f32 (alias: hidA 16KB)
    char*  hidA        = sm + 16384;                     // [16] rows x 1024B swz
    float* dsum        = (float*)(sm + 33280);           // [16][4]
    float* red         = (float*)(sm + 33536);           // [16][8]
    const int t = threadIdx.x, w = t >> 6, l = t & 63;
    const int n = l & 15, lg = l >> 4;
    const int R0 = blockIdx.x * 16;
    const f32x4 fz = {0.f, 0.f, 0.f, 0.f};

    // ---- stage 1: reduce partials, load slots_prev
    {
        float us[16];
#pragma unroll
        for (int m = 0; m < 16; ++m) {
            const int gr = R0 + m, bb = gr >> 3, q = gr & 7;
            float s = 0.f;
#pragma unroll
            for (int c = 0; c < 16; ++c)
                s += updp[(((size_t)(bb * 16 + c)) * 8 + q) * 256 + t];
            us[m] = s;
        }
        if (t < 64) {
            const int m = t >> 2, h = t & 3;
            const int gr = R0 + m, bb = gr >> 3, q = gr & 7;
            float s = 0.f;
#pragma unroll
            for (int c = 0; c < 16; ++c)
                s += denp[(size_t)(bb * 16 + c) * 32 + h * 8 + q];
            dsum[m * 4 + h] = s;
        }
#pragma unroll
        for (int m = 0; m < 16; ++m) {
            const float hv = slots[(size_t)(R0 + m) * 256 + t];
            hf32[m * 264 + t] = hv;
            *(unsigned short*)((char*)hA + m * 512 + ((t * 2) ^ ((m & 7) << 4))) = f2bf(hv);
        }
        __syncthreads();
        const int h = t >> 6;
#pragma unroll
        for (int m = 0; m < 16; ++m) {
            const float inv = 1.f / (dsum[m * 4 + h] + (float)KK * EPS);
            *(unsigned short*)((char*)uA + m * 512 + ((t * 2) ^ ((m & 7) << 4))) = f2bf(us[m] * inv);
        }
    }
    __syncthreads();

    // ---- stage 2: GRU GEMMs (two passes to cap VGPR), gates
    f32x4 sv[4];
    {
        f32x4 ai0[4], ai1[4], ai2[4];
#pragma unroll
        for (int nf = 0; nf < 4; ++nf) { ai0[nf] = fz; ai1[nf] = fz; ai2[nf] = fz; }
#pragma unroll
        for (int kk = 0; kk < 8; ++kk) {
            const bf16x8 au = *(const bf16x8*)((char*)uA + n * 512 + ((kk * 64 + lg * 16) ^ ((n & 7) << 4)));
            const int kidx = kk * 32 + lg * 8;
#pragma unroll
            for (int nf = 0; nf < 4; ++nf) {
                const int col = w * 64 + nf * 16 + n;
                const bf16x8 br = *(const bf16x8*)(Wihbf + (size_t)col * 256 + kidx);
                const bf16x8 bz = *(const bf16x8*)(Wihbf + (size_t)(256 + col) * 256 + kidx);
                const bf16x8 bn = *(const bf16x8*)(Wihbf + (size_t)(512 + col) * 256 + kidx);
                ai0[nf] = MFMA(au, br, ai0[nf], 0, 0, 0);
                ai1[nf] = MFMA(au, bz, ai1[nf], 0, 0, 0);
                ai2[nf] = MFMA(au, bn, ai2[nf], 0, 0, 0);
            }
        }
        f32x4 ah0[4], ah1[4], ah2[4];
#pragma unroll
        for (int nf = 0; nf < 4; ++nf) { ah0[nf] = fz; ah1[nf] = fz; ah2[nf] = fz; }
#pragma unroll
        for (int kk = 0; kk < 8; ++kk) {
            const bf16x8 ah_ = *(const bf16x8*)((char*)hA + n * 512 + ((kk * 64 + lg * 16) ^ ((n & 7) << 4)));
            const int kidx = kk * 32 + lg * 8;
#pragma unroll
            for (int nf = 0; nf < 4; ++nf) {
                const int col = w * 64 + nf * 16 + n;
                const bf16x8 cr = *(const bf16x8*)(Whhbf + (size_t)col * 256 + kidx);
                const bf16x8 cz = *(const bf16x8*)(Whhbf + (size_t)(256 + col) * 256 + kidx);
                const bf16x8 cn = *(const bf16x8*)(Whhbf + (size_t)(512 + col) * 256 + kidx);
                ah0[nf] = MFMA(ah_, cr, ah0[nf], 0, 0, 0);
                ah1[nf] = MFMA(ah_, cz, ah1[nf], 0, 0, 0);
                ah2[nf] = MFMA(ah_, cn, ah2[nf], 0, 0, 0);
            }
        }
#pragma unroll
        for (int nf = 0; nf < 4; ++nf) {
            const int col = w * 64 + nf * 16 + n;
            const float br_ = bih[col], bz_ = bih[256 + col], bn_ = bih[512 + col];
            const float cr_ = bhh[col], cz_ = bhh[256 + col], cn_ = bhh[512 + col];
#pragma unroll
            for (int r = 0; r < 4; ++r) {
                const int rowm = lg * 4 + r;
                const float ir = ai0[nf][r] + br_, iz = ai1[nf][r] + bz_, inn = ai2[nf][r] + bn_;
                const float hr = ah0[nf][r] + cr_, hz = ah1[nf][r] + cz_, hn = ah2[nf][r] + cn_;
                const float rg = 1.f / (1.f + __expf(-(ir + hr)));
                const float zg = 1.f / (1.f + __expf(-(iz + hz)));
                const float ng = tanhf(inn + rg * hn);
                const float h0v = hf32[rowm * 264 + col];
                sv[nf][r] = (1.f - zg) * ng + zg * h0v;
            }
        }
    }
    // LN(mlp) -> mA (aliases uA; internal barrier orders prior uA/hf32 reads)
    ln_rows(sv, (char*)uA, red, lnmw, lnmb, w, n, lg, w * 64 + n);
    __syncthreads();

    // ---- stage 3: MLP1 (N=512; wave owns 128 cols)
    {
        f32x4 m1[8];
#pragma unroll
        for (int nf = 0; nf < 8; ++nf) m1[nf] = fz;
#pragma unroll
        for (int kk = 0; kk < 8; ++kk) {
            const bf16x8 a = *(const bf16x8*)((char*)uA + n * 512 + ((kk * 64 + lg * 16) ^ ((n & 7) << 4)));
            const int kidx = kk * 32 + lg * 8;
#pragma unroll
            for (int nf = 0; nf < 8; ++nf) {
                const int colh = w * 128 + nf * 16 + n;
                const bf16x8 bb = *(const bf16x8*)(W1T + (size_t)colh * 256 + kidx);
                m1[nf] = MFMA(a, bb, m1[nf], 0, 0, 0);
            }
        }
        __syncthreads();   // all waves done with mA reads & hf32 is long dead -> hidA writable
#pragma unroll
        for (int nf = 0; nf < 8; ++nf) {
            const int colh = w * 128 + nf * 16 + n;
            const float bb = b1[colh];
#pragma unroll
            for (int r = 0; r < 4; ++r) {
                const int rowm = lg * 4 + r;
                *(unsigned short*)(hidA + rowm * 1024 + ((colh * 2) ^ ((rowm & 7) << 4)))
                    = f2bf(fmaxf(m1[nf][r] + bb, 0.f));
            }
        }
    }
    __syncthreads();

    // ---- stage 4: MLP2 (K=512) + residual -> slots
    {
        f32x4 m2[4];
#pragma unroll
        for (int nf = 0; nf < 4; ++nf) m2[nf] = fz;
#pragma unroll
        for (int kk = 0; kk < 16; ++kk) {
            const bf16x8 a = *(const bf16x8*)(hidA + n * 1024 + ((kk * 64 + lg * 16) ^ ((n & 7) << 4)));
            const int kidx = kk * 32 + lg * 8;
#pragma unroll
            for (int nf = 0; nf < 4; ++nf) {
                const int col = w * 64 + nf * 16 + n;
                const bf16x8 bb = *(const bf16x8*)(W2T + (size_t)col * 512 + kidx);
                m2[nf] = MFMA(a, bb, m2[nf], 0, 0, 0);
            }
        }
#pragma unroll
        for (int nf = 0; nf < 4; ++nf) {
            const int col = w * 64 + nf * 16 + n;
            const float bb = b2[col];
#pragma unroll
            for (int r = 0; r < 4; ++r) {
                const int rowm = lg * 4 + r;
                const float v = m2[nf][r] + bb + sv[nf][r];
                sv[nf][r] = v;
                slots[(size_t)(R0 + rowm) * 256 + col] = v;
            }
        }
    }
    // LN(slots) -> mqA (aliases hA)
    ln_rows(sv, (char*)hA, red, lnsw, lnsb, w, n, lg, w * 64 + n);
    __syncthreads();

    // ---- stage 5: q projection
    {
        f32x4 qa[4];
#pragma unroll
        for (int nf = 0; nf < 4; ++nf) qa[nf] = fz;
#pragma unroll
        for (int kk = 0; kk < 8; ++kk) {
            const bf16x8 a = *(const bf16x8*)((char*)hA + n * 512 + ((kk * 64 + lg * 16) ^ ((n & 7) << 4)));
            const int kidx = kk * 32 + lg * 8;
#pragma unroll
            for (int nf = 0; nf < 4; ++nf) {
                const int col = w * 64 + nf * 16 + n;
                const bf16x8 bb = *(const bf16x8*)(WqT + (size_t)col * 256 + kidx);
                qa[nf] = MFMA(a, bb, qa[nf], 0, 0, 0);
            }
        }
#pragma unroll
        for (int nf = 0; nf < 4; ++nf) {
            const int col = w * 64 + nf * 16 + n;
#pragma unroll
            for (int r = 0; r < 4; ++r)
                qbuf[(size_t)(R0 + lg * 4 + r) * 256 + col] = qa[nf][r];
        }
    }
}

__global__ void k_den(const float* __restrict__ denp, float* __restrict__ invden)
{
    const int b = blockIdx.x, t = threadIdx.x;  // 32 threads
    float s = 0.f;
#pragma unroll
    for (int c = 0; c < NCH; ++c) s += denp[((size_t)b * NCH + c) * HQ + t];
    invden[b * HQ + t] = 1.f / (s + (float)KK * EPS);
}

__global__ void k7_copy(const float* __restrict__ s, float* __restrict__ o)
{
    const int i = blockIdx.x * 256 + threadIdx.x;
    o[i] = s[i];
}

__global__ __launch_bounds__(256) void k7_attnout(
    const float* __restrict__ pbuf, const float* __restrict__ invden, float* __restrict__ out2)
{
    const int blk = blockIdx.x;
    const int b = blk >> 4;
    const int kk0 = (blk & 15) * 256;
    __shared__ float ps[256][33];
    __shared__ float inv[32];
    const int t = threadIdx.x;
    const float* pp = pbuf + ((size_t)b * KK + kk0) * HQ;
    for (int i = 0; i < 32; ++i) {
        const int idx = i * 256 + t;
        ps[idx >> 5][idx & 31] = pp[idx];
    }
    if (t < 32) inv[t] = invden[b * HQ + t];
    __syncthreads();
    float* o = out2 + (size_t)b * Q * KK + kk0 + t;
#pragma unroll
    for (int q = 0; q < 8; ++q) {
        float v = 0.f;
#pragma unroll
        for (int hh = 0; hh < 4; ++hh)
            v += (ps[t][hh * 8 + q] + EPS) * inv[hh * 8 + q];
        o[(size_t)q * KK] = v * 0.25f;
    }
}

extern "C" void kernel_launch(void* const* d_in, const int* in_sizes, int n_in,
                              void* d_out, int out_size, void* d_ws, size_t ws_size,
                              hipStream_t stream)
{
    const float* inputs  = (const float*)d_in[0];
    const float* slots0  = (const float*)d_in[1];
    const float* Wq      = (const float*)d_in[2];
    const float* Wk      = (const float*)d_in[3];
    const float* Wv      = (const float*)d_in[4];
    const float* ln_in_w = (const float*)d_in[5];
    const float* ln_in_b = (const float*)d_in[6];
    const float* ln_s_w  = (const float*)d_in[7];
    const float* ln_s_b  = (const float*)d_in[8];
    const float* ln_m_w  = (const float*)d_in[9];
    const float* ln_m_b  = (const float*)d_in[10];
    const float* gWih    = (const float*)d_in[11];
    const float* gWhh    = (const float*)d_in[12];
    const float* gbih    = (const float*)d_in[13];
    const float* gbhh    = (const float*)d_in[14];
    const float* W1      = (const float*)d_in[15];
    const float* b1      = (const float*)d_in[16];
    const float* W2      = (const float*)d_in[17];
    const float* b2      = (const float*)d_in[18];

    char* p = (char*)d_ws;
    unsigned short* kbuf  = (unsigned short*)p; p += (size_t)B * KK * D * 2;
    unsigned short* vbufT = (unsigned short*)p; p += (size_t)B * KK * D * 2;
    float* pbuf   = (float*)p; p += (size_t)B * KK * HQ * 4;
    float* updp   = (float*)p; p += (size_t)B * NCH * Q * D * 4;
    float* denp   = (float*)p; p += (size_t)B * NCH * HQ * 4;
    float* invden = (float*)p; p += (size_t)B * HQ * 4;
    float* qbuf   = (float*)p; p += (size_t)B * Q * D * 4;
    float* slots  = (float*)p; p += (size_t)B * Q * D * 4;
    unsigned short* WkvT  = (unsigned short*)p; p += (size_t)512 * 256 * 2;
    unsigned short* Wihbf = (unsigned short*)p; p += (size_t)768 * 256 * 2;
    unsigned short* Whhbf = (unsigned short*)p; p += (size_t)768 * 256 * 2;
    unsigned short* W1T   = (unsigned short*)p; p += (size_t)HM * 256 * 2;
    unsigned short* W2T   = (unsigned short*)p; p += (size_t)256 * HM * 2;
    unsigned short* WqT   = (unsigned short*)p; p += (size_t)256 * 256 * 2;
    // total ws used: ~337 MB

    k_init<<<(B * Q * D) / 256, 256, 0, stream>>>(slots0, slots);
    k0_wkv<<<512, 256, 0, stream>>>(Wk, Wv, WkvT);
    k0_cvt<<<768, 256, 0, stream>>>(gWih, Wihbf);
    k0_cvt<<<768, 256, 0, stream>>>(gWhh, Whhbf);
    k0_t1<<<512, 256, 0, stream>>>(W1, W1T);
    k0_t2<<<256, 256, 0, stream>>>(W2, W2T);
    k0_wq<<<256, 256, 0, stream>>>(Wq, WqT);
    k1_mfma<<<(B * KK) / 64, 256, 0, stream>>>(inputs, WkvT, ln_in_w, ln_in_b, kbuf, vbufT);
    k2_qproj<<<B * Q, 256, 0, stream>>>(slots, Wq, ln_s_w, ln_s_b, qbuf);
    for (int it = 0; it < 3; ++it) {
        k_attn<<<B * NCH, 256, 0, stream>>>(kbuf, vbufT, qbuf, updp, denp, pbuf, (it == 2) ? 1 : 0);
        k_slot<<<32, 256, 0, stream>>>(updp, denp, slots, Wihbf, Whhbf, gbih, gbhh,
                                       W1T, b1, W2T, b2, ln_m_w, ln_m_b, WqT,
                                       ln_s_w, ln_s_b, qbuf);
    }
    k_den<<<B, 32, 0, stream>>>(denp, invden);
    k7_copy<<<(B * Q * D) / 256, 256, 0, stream>>>(slots, (float*)d_out);
    k7_attnout<<<B * (KK / 256), 256, 0, stream>>>(pbuf, invden, (float*)d_out + (size_t)B * Q * D);
}

// Round 5
// 551.564 us; speedup vs baseline: 1.0613x; 1.0613x over previous
//
#include <hip/hip_runtime.h>

#define B   64
#define KK  4096
#define D   256
#define Q   8
#define H   4
#define DH  64
#define HQ  32
#define HM  512
#define NCH 16
#define CHK 256
#define EPS 1e-8f
#define LNE 1e-5f
#define SCALE 0.125f

typedef short bf16x8 __attribute__((ext_vector_type(8)));
typedef float f32x4 __attribute__((ext_vector_type(4)));

#define MFMA __builtin_amdgcn_mfma_f32_16x16x32_bf16

__device__ __forceinline__ float bf2f(unsigned short u) {
    unsigned int x = ((unsigned int)u) << 16;
    float f; __builtin_memcpy(&f, &x, 4); return f;
}
__device__ __forceinline__ unsigned short f2bf(float f) {
    unsigned int x; __builtin_memcpy(&x, &f, 4);
    unsigned int lsb = (x >> 16) & 1u;
    x += 0x7fffu + lsb;
    return (unsigned short)(x >> 16);
}

__device__ __forceinline__ void gload16(const void* g, void* l) {
    __builtin_amdgcn_global_load_lds(
        (const __attribute__((address_space(1))) unsigned int*)g,
        (__attribute__((address_space(3))) unsigned int*)l, 16, 0, 0);
}

// ---------------- fused prep: all weight transforms + slots init ------------
__global__ __launch_bounds__(256) void k_prep(
    const float* __restrict__ Wk, const float* __restrict__ Wv,
    const float* __restrict__ gWih, const float* __restrict__ gWhh,
    const float* __restrict__ W1, const float* __restrict__ W2,
    const float* __restrict__ Wq, const float* __restrict__ s0,
    unsigned short* __restrict__ WkvT, unsigned short* __restrict__ Wihbf,
    unsigned short* __restrict__ Whhbf, unsigned short* __restrict__ W1T,
    unsigned short* __restrict__ W2T, unsigned short* __restrict__ WqT,
    float* __restrict__ slots)
{
    const int blk = blockIdx.x, t = threadIdx.x;
    if (blk < 512) {                      // WkvT[c][d]
        const int c = blk;
        const float v = (c < 256) ? Wk[(size_t)t * 256 + c] * SCALE
                                  : Wv[(size_t)t * 256 + (c - 256)];
        WkvT[(size_t)c * 256 + t] = f2bf(v);
    } else if (blk < 1280) {              // Wih cvt
        const int i = (blk - 512) * 256 + t;
        Wihbf[i] = f2bf(gWih[i]);
    } else if (blk < 2048) {              // Whh cvt
        const int i = (blk - 1280) * 256 + t;
        Whhbf[i] = f2bf(gWhh[i]);
    } else if (blk < 2560) {              // W1T [512][256]
        const int nn = blk - 2048;
        W1T[(size_t)nn * 256 + t] = f2bf(W1[(size_t)t * 512 + nn]);
    } else if (blk < 2816) {              // W2T [256][512]
        const int nn = blk - 2560;
        W2T[(size_t)nn * 512 + t]       = f2bf(W2[(size_t)t * 256 + nn]);
        W2T[(size_t)nn * 512 + 256 + t] = f2bf(W2[(size_t)(256 + t) * 256 + nn]);
    } else if (blk < 3072) {              // WqT [256][256]
        const int nn = blk - 2816;
        WqT[(size_t)nn * 256 + t] = f2bf(Wq[(size_t)t * 256 + nn]);
    } else {                              // slots init
        const int i = (blk - 3072) * 256 + t;
        slots[i] = s0[i];
    }
}

// ---------------- K1: LN + K/V projection -> fragment-packed K/V ------------
// kpk: [b][k>>4][d>>5] 1KB subtiles, elem = lane*8 + (d&7), lane = (k&15)+((d&31)>>3)*16
// vpk: [b][k>>5][d>>4] 1KB subtiles, elem = lane*8 + (k&7), lane = (d&15)+((k&31)>>3)*16
__global__ __launch_bounds__(256) void k1_mfma(
    const float* __restrict__ inp, const unsigned short* __restrict__ WkvT,
    const float* __restrict__ lnw, const float* __restrict__ lnb,
    unsigned short* __restrict__ kpk, unsigned short* __restrict__ vpk)
{
    __shared__ char smem[49152];
    char* abase = smem;            // 32KB A (dead after hoist)
    char* bb0 = smem + 32768;      // 16KB B buf0
    char* bb1 = smem;              // 16KB B buf1 (aliases A)
    const int t = threadIdx.x, w = t >> 6, l = t & 63;
    const size_t row0 = (size_t)blockIdx.x * 64;
    const int b_blk = blockIdx.x >> 6;          // batch (64 rows never cross b)
    const int kbase = (blockIdx.x & 63) * 64;   // k offset within batch

    auto stageB = [&](int n2, char* dst) {
#pragma unroll
        for (int i = 0; i < 4; ++i) {
            const int seg = w * 4 + i;
            const int r = seg * 2 + (l >> 5);
            const int off = ((l & 31) * 16) ^ ((r & 7) << 4);
            gload16((const char*)WkvT + ((size_t)n2 * 32 + r) * 512 + off, dst + seg * 1024);
        }
    };
    stageB(0, bb0);

    float4 xv[16];
#pragma unroll
    for (int i = 0; i < 16; ++i)
        xv[i] = ((const float4*)(inp + (row0 + w * 16 + i) * D))[l];
    const float4 w4 = ((const float4*)lnw)[l];
    const float4 b4 = ((const float4*)lnb)[l];
#pragma unroll
    for (int i = 0; i < 16; ++i) {
        const int r = w * 16 + i;
        float4 x = xv[i];
        float s  = x.x + x.y + x.z + x.w;
        float ss = x.x*x.x + x.y*x.y + x.z*x.z + x.w*x.w;
#pragma unroll
        for (int off = 32; off; off >>= 1) { s += __shfl_xor(s, off); ss += __shfl_xor(ss, off); }
        const float mu = s * (1.f / 256.f);
        const float rs = rsqrtf(ss * (1.f / 256.f) - mu * mu + LNE);
        ushort4 pk;
        pk.x = f2bf((x.x - mu) * rs * w4.x + b4.x);
        pk.y = f2bf((x.y - mu) * rs * w4.y + b4.y);
        pk.z = f2bf((x.z - mu) * rs * w4.z + b4.z);
        pk.w = f2bf((x.w - mu) * rs * w4.w + b4.w);
        *(ushort4*)(abase + r * 512 + ((l * 8) ^ ((r & 7) << 4))) = pk;
    }
    __syncthreads();                        // A ready, B0 landed

    const int arow = w * 16 + (l & 15);
    const char* ap = abase + arow * 512;
    const int asw = (l & 7) << 4;
    bf16x8 af[8];
#pragma unroll
    for (int kk = 0; kk < 8; ++kk)
        af[kk] = *(const bf16x8*)(ap + ((kk * 64 + (l >> 4) * 16) ^ asw));
    __syncthreads();                        // hoists done; A region dead
    stageB(1, bb1);

    const int lg = l >> 4;
    const f32x4 fz = {0.f, 0.f, 0.f, 0.f};
    for (int n2 = 0; n2 < 16; ++n2) {
        const char* bbase = (n2 & 1) ? bb1 : bb0;
        f32x4 acc[2] = {fz, fz};
        if (n2 < 8) {
            // K half: swapped operands -> C[d][k]
#pragma unroll
            for (int kk = 0; kk < 8; ++kk) {
                const int koff = kk * 64 + lg * 16;
#pragma unroll
                for (int nf = 0; nf < 2; ++nf) {
                    const int brow = nf * 16 + (l & 15);
                    const bf16x8 bf_ = *(const bf16x8*)(bbase + brow * 512 + (koff ^ ((brow & 7) << 4)));
                    acc[nf] = MFMA(bf_, af[kk], acc[nf], 0, 0, 0);
                }
            }
            // lane: k = row0 + w*16 + (l&15); d = n2*32 + nf*16 + lg*4 + reg
            const int kt16 = (kbase >> 4) + w;
#pragma unroll
            for (int nf = 0; nf < 2; ++nf) {
                unsigned short* kp = kpk
                    + ((((size_t)b_blk * 256 + kt16) * 8 + n2) * 512)
                    + ((l & 15) + ((nf * 2 + (lg >> 1)) << 4)) * 8 + (lg & 1) * 4;
                ushort4 pk;
                pk.x = f2bf(acc[nf][0]); pk.y = f2bf(acc[nf][1]);
                pk.z = f2bf(acc[nf][2]); pk.w = f2bf(acc[nf][3]);
                *(ushort4*)kp = pk;
            }
        } else {
            // V half: normal orientation -> C[k][d]
#pragma unroll
            for (int kk = 0; kk < 8; ++kk) {
                const int koff = kk * 64 + lg * 16;
#pragma unroll
                for (int nf = 0; nf < 2; ++nf) {
                    const int brow = nf * 16 + (l & 15);
                    const bf16x8 bf_ = *(const bf16x8*)(bbase + brow * 512 + (koff ^ ((brow & 7) << 4)));
                    acc[nf] = MFMA(af[kk], bf_, acc[nf], 0, 0, 0);
                }
            }
            // lane: d = (n2-8)*32 + nf*16 + (l&15); k = row0 + w*16 + lg*4 + reg
            const int kt32 = (kbase >> 5) + (w >> 1);
#pragma unroll
            for (int nf = 0; nf < 2; ++nf) {
                const int dt16 = (n2 - 8) * 2 + nf;
                unsigned short* vp = vpk
                    + ((((size_t)b_blk * 128 + kt32) * 16 + dt16) * 512)
                    + ((l & 15) + (((w & 1) * 2 + (lg >> 1)) << 4)) * 8 + (lg & 1) * 4;
                ushort4 pk;
                pk.x = f2bf(acc[nf][0]); pk.y = f2bf(acc[nf][1]);
                pk.z = f2bf(acc[nf][2]); pk.w = f2bf(acc[nf][3]);
                *(ushort4*)vp = pk;
            }
        }
        __syncthreads();                    // buf reads done; stage(n2+1) landed
        if (n2 < 14) stageB(n2 + 2, (n2 & 1) ? bb1 : bb0);
    }
}

// ---------------- K2: LN(slots) + q projection (iter 0 only) ----------------
__global__ __launch_bounds__(256) void k2_qproj(
    const float* __restrict__ slots, const float* __restrict__ Wq,
    const float* __restrict__ lnw, const float* __restrict__ lnb, float* __restrict__ qbuf)
{
    const int row = blockIdx.x, t = threadIdx.x;
    __shared__ float sn[256];
    __shared__ float red[8];
    const float x = slots[(size_t)row * D + t];
    float mu, rs;
    {
        float s = x, ss = x * x;
#pragma unroll
        for (int off = 32; off; off >>= 1) { s += __shfl_xor(s, off); ss += __shfl_xor(ss, off); }
        if ((t & 63) == 0) { red[t >> 6] = s; red[4 + (t >> 6)] = ss; }
        __syncthreads();
        const float S  = red[0] + red[1] + red[2] + red[3];
        const float SS = red[4] + red[5] + red[6] + red[7];
        mu = S * (1.f / 256.f);
        rs = rsqrtf(SS * (1.f / 256.f) - mu * mu + LNE);
    }
    sn[t] = (x - mu) * rs * lnw[t] + lnb[t];
    __syncthreads();
    float acc = 0.f;
    for (int d = 0; d < 256; ++d) acc = fmaf(sn[d], Wq[(size_t)d * 256 + t], acc);
    qbuf[(size_t)row * D + t] = acc;
}

// ---------------- fused attention: packed K/V, coalesced 1KB wave-loads -----
__global__ __launch_bounds__(256) void k_attn(
    const unsigned short* __restrict__ kpk, const unsigned short* __restrict__ vpk,
    const float* __restrict__ qbuf, float* __restrict__ updp,
    float* __restrict__ denp, float* __restrict__ pbuf, int write_p)
{
    __shared__ unsigned short psm[2][2048];    // P^T dbuf [32 hq][64 k], swizzled
    __shared__ float dred[4][32];
    const int t = threadIdx.x, w = t >> 6, l = t & 63;
    const int b = blockIdx.x >> 4, chunk = blockIdx.x & 15;
    const int k0g = chunk * CHK;
    const int n = l & 15, lg = l >> 4;

    // q fragments (block-diagonal Q32)
    bf16x8 qf[2][2];
#pragma unroll
    for (int p = 0; p < 2; ++p) {
        const int h = p * 2 + (n >> 3);
        const float* qb = qbuf + ((size_t)b * Q + (n & 7)) * D;
#pragma unroll
        for (int j = 0; j < 2; ++j) {
            const int dbase = (h * 2 + j) * 32 + lg * 8;
            short tmp[8];
#pragma unroll
            for (int e = 0; e < 8; ++e) tmp[e] = (short)f2bf(qb[dbase + e]);
            __builtin_memcpy(&qf[p][j], tmp, 16);
        }
    }
    const bf16x8 ZV = {0,0,0,0,0,0,0,0};
    const f32x4 fz = {0.f,0.f,0.f,0.f};
    f32x4 pv[2][4];
#pragma unroll
    for (int mt = 0; mt < 2; ++mt)
#pragma unroll
        for (int nf = 0; nf < 4; ++nf) pv[mt][nf] = fz;
    float den0 = 0.f, den1 = 0.f;

    // packed bases: fully coalesced (lane l reads bytes l*16..+16 of 1KB subtile)
    const unsigned short* kb0 = kpk + (((size_t)(b * 256 + chunk * 16 + w)) * 8) * 512 + l * 8;
    const unsigned short* vb0 = vpk + (((size_t)(b * 128 + chunk * 8) * 16) + w * 4) * 512 + l * 8;

    for (int tile = 0; tile < 4; ++tile) {
        bf16x8 kf[8];
#pragma unroll
        for (int kk = 0; kk < 8; ++kk)
            kf[kk] = *(const bf16x8*)(kb0 + (size_t)tile * 16384 + kk * 512);
        f32x4 lac[2] = {fz, fz};
#pragma unroll
        for (int kk = 0; kk < 8; ++kk) {
            const int p = kk >> 2;
            const bool on = (((kk & 3) >> 1) == (n >> 3));
            const bf16x8 bq = on ? qf[p][kk & 1] : ZV;
            if (p == 0) lac[0] = MFMA(kf[kk], bq, lac[0], 0, 0, 0);
            else        lac[1] = MFMA(kf[kk], bq, lac[1], 0, 0, 0);
        }
        // joint softmax over 32 (h,q) per k-row
#pragma unroll
        for (int reg = 0; reg < 4; ++reg) {
            float m = fmaxf(lac[0][reg], lac[1][reg]);
#pragma unroll
            for (int off = 8; off; off >>= 1) m = fmaxf(m, __shfl_xor(m, off));
            const float e0 = __expf(lac[0][reg] - m);
            const float e1 = __expf(lac[1][reg] - m);
            float se = e0 + e1;
#pragma unroll
            for (int off = 8; off; off >>= 1) se += __shfl_xor(se, off);
            const float inv = 1.f / se;
            lac[0][reg] = e0 * inv; lac[1][reg] = e1 * inv;
            den0 += lac[0][reg];    den1 += lac[1][reg];
        }
        // write P^T to psm[tile&1] (safe: PV(tile-1) used the other buffer)
        char* pb = (char*)psm[tile & 1];
        const int kb = w * 16 + lg * 4;
        {
            ushort4 p0, p1;
            p0.x = f2bf(lac[0][0]); p0.y = f2bf(lac[0][1]); p0.z = f2bf(lac[0][2]); p0.w = f2bf(lac[0][3]);
            p1.x = f2bf(lac[1][0]); p1.y = f2bf(lac[1][1]); p1.z = f2bf(lac[1][2]); p1.w = f2bf(lac[1][3]);
            *(ushort4*)(pb + n * 128 + ((kb * 2) ^ ((n & 7) << 4))) = p0;
            *(ushort4*)(pb + (16 + n) * 128 + ((kb * 2) ^ ((n & 7) << 4))) = p1;
        }
        if (write_p) {
            float* pp = pbuf + ((size_t)b * KK + k0g + tile * 64 + kb) * HQ;
#pragma unroll
            for (int reg = 0; reg < 4; ++reg) {
                pp[(size_t)reg * HQ + n] = lac[0][reg];
                pp[(size_t)reg * HQ + 16 + n] = lac[1][reg];
            }
        }
        __syncthreads();     // psm[tile&1] ready for all waves
        // PV: V frags direct from packed global
#pragma unroll
        for (int kkp = 0; kkp < 2; ++kkp) {
            const int koff = kkp * 64 + lg * 16;
            const bf16x8 a0 = *(const bf16x8*)(pb + n * 128 + (koff ^ ((n & 7) << 4)));
            const bf16x8 a1 = *(const bf16x8*)(pb + (16 + n) * 128 + (koff ^ ((n & 7) << 4)));
#pragma unroll
            for (int nf = 0; nf < 4; ++nf) {
                const bf16x8 bv = *(const bf16x8*)(vb0 + (tile * 32 + kkp * 16 + nf) * 512);
                pv[0][nf] = MFMA(a0, bv, pv[0][nf], 0, 0, 0);
                pv[1][nf] = MFMA(a1, bv, pv[1][nf], 0, 0, 0);
            }
        }
    }

    den0 += __shfl_xor(den0, 16); den0 += __shfl_xor(den0, 32);
    den1 += __shfl_xor(den1, 16); den1 += __shfl_xor(den1, 32);
    if (l < 16) { dred[w][l] = den0; dred[w][16 + l] = den1; }
    __syncthreads();
    if (t < 32)
        denp[((size_t)b * NCH + chunk) * HQ + t] =
            dred[0][t] + dred[1][t] + dred[2][t] + dred[3][t];

    if ((lg >> 1) == (w & 1)) {
        const int mt = w >> 1;
#pragma unroll
        for (int nf = 0; nf < 4; ++nf) {
#pragma unroll
            for (int reg = 0; reg < 4; ++reg) {
                const int q = (lg & 1) * 4 + reg;
                updp[(((size_t)b * NCH + chunk) * Q + q) * D + w * 64 + nf * 16 + n] = pv[mt][nf][reg];
            }
        }
    }
}

// ---------------- LN helper for k_slot ----------------
__device__ __forceinline__ void ln_rows(const f32x4 sv[4], char* dstA, float* red,
    const float* __restrict__ lnw, const float* __restrict__ lnb,
    int w, int n, int lg, int col0)
{
    float ps[4], pq[4];
#pragma unroll
    for (int r = 0; r < 4; ++r) {
        float s = 0.f, q2 = 0.f;
#pragma unroll
        for (int nf = 0; nf < 4; ++nf) { const float v = sv[nf][r]; s += v; q2 += v * v; }
#pragma unroll
        for (int off = 1; off < 16; off <<= 1) { s += __shfl_xor(s, off); q2 += __shfl_xor(q2, off); }
        ps[r] = s; pq[r] = q2;
    }
    if (n == 0) {
#pragma unroll
        for (int r = 0; r < 4; ++r) {
            red[(lg * 4 + r) * 8 + w * 2]     = ps[r];
            red[(lg * 4 + r) * 8 + w * 2 + 1] = pq[r];
        }
    }
    __syncthreads();
    float mu[4], rs[4];
#pragma unroll
    for (int r = 0; r < 4; ++r) {
        const int rowm = lg * 4 + r;
        const float S  = red[rowm*8+0] + red[rowm*8+2] + red[rowm*8+4] + red[rowm*8+6];
        const float SS = red[rowm*8+1] + red[rowm*8+3] + red[rowm*8+5] + red[rowm*8+7];
        mu[r] = S * (1.f / 256.f);
        rs[r] = rsqrtf(SS * (1.f / 256.f) - mu[r] * mu[r] + LNE);
    }
#pragma unroll
    for (int nf = 0; nf < 4; ++nf) {
        const int col = col0 + nf * 16;
        const float wv = lnw[col], bv = lnb[col];
#pragma unroll
        for (int r = 0; r < 4; ++r) {
            const int rowm = lg * 4 + r;
            const float mval = (sv[nf][r] - mu[r]) * rs[r] * wv + bv;
            *(unsigned short*)(dstA + rowm * 512 + ((col * 2) ^ ((rowm & 7) << 4))) = f2bf(mval);
        }
    }
}

// ---------------- fused slot update: reduce+GRU+LN+MLP+LN+qproj -------------
__global__ __launch_bounds__(256) void k_slot(
    const float* __restrict__ updp, const float* __restrict__ denp,
    float* __restrict__ slots,
    const unsigned short* __restrict__ Wihbf, const unsigned short* __restrict__ Whhbf,
    const float* __restrict__ bih, const float* __restrict__ bhh,
    const unsigned short* __restrict__ W1T, const float* __restrict__ b1,
    const unsigned short* __restrict__ W2T, const float* __restrict__ b2,
    const float* __restrict__ lnmw, const float* __restrict__ lnmb,
    const unsigned short* __restrict__ WqT,
    const float* __restrict__ lnsw, const float* __restrict__ lnsb,
    float* __restrict__ qbuf)
{
    __shared__ char sm[34304];
    unsigned short* uA = (unsigned short*)(sm);          // [16] rows x 512B swz (alias: mA)
    unsigned short* hA = (unsigned short*)(sm + 8192);   // (alias: mqA)
    float* hf32        = (float*)(sm + 16384);           // [16][264] f32 (alias: hidA 16KB)
    char*  hidA        = sm + 16384;                     // [16] rows x 1024B swz
    float* dsum        = (float*)(sm + 33280);           // [16][4]
    float* red         = (float*)(sm + 33536);           // [16][8]
    const int t = threadIdx.x, w = t >> 6, l = t & 63;
    const int n = l & 15, lg = l >> 4;
    const int R0 = blockIdx.x * 16;
    const f32x4 fz = {0.f, 0.f, 0.f, 0.f};

    // ---- stage 1: reduce partials, load slots_prev
    {
        float us[16];
#pragma unroll
        for (int m = 0; m < 16; ++m) {
            const int gr = R0 + m, bb = gr >> 3, q = gr & 7;
            float s = 0.f;
#pragma unroll
            for (int c = 0; c < 16; ++c)
                s += updp[(((size_t)(bb * 16 + c)) * 8 + q) * 256 + t];
            us[m] = s;
        }
        if (t < 64) {
            const int m = t >> 2, h = t & 3;
            const int gr = R0 + m, bb = gr >> 3, q = gr & 7;
            float s = 0.f;
#pragma unroll
            for (int c = 0; c < 16; ++c)
                s += denp[(size_t)(bb * 16 + c) * 32 + h * 8 + q];
            dsum[m * 4 + h] = s;
        }
#pragma unroll
        for (int m = 0; m < 16; ++m) {
            const float hv = slots[(size_t)(R0 + m) * 256 + t];
            hf32[m * 264 + t] = hv;
            *(unsigned short*)((char*)hA + m * 512 + ((t * 2) ^ ((m & 7) << 4))) = f2bf(hv);
        }
        __syncthreads();
        const int h = t >> 6;
#pragma unroll
        for (int m = 0; m < 16; ++m) {
            const float inv = 1.f / (dsum[m * 4 + h] + (float)KK * EPS);
            *(unsigned short*)((char*)uA + m * 512 + ((t * 2) ^ ((m & 7) << 4))) = f2bf(us[m] * inv);
        }
    }
    __syncthreads();

    // ---- stage 2: GRU GEMMs + gates
    f32x4 sv[4];
    {
        f32x4 ai0[4], ai1[4], ai2[4];
#pragma unroll
        for (int nf = 0; nf < 4; ++nf) { ai0[nf] = fz; ai1[nf] = fz; ai2[nf] = fz; }
#pragma unroll
        for (int kk = 0; kk < 8; ++kk) {
            const bf16x8 au = *(const bf16x8*)((char*)uA + n * 512 + ((kk * 64 + lg * 16) ^ ((n & 7) << 4)));
            const int kidx = kk * 32 + lg * 8;
#pragma unroll
            for (int nf = 0; nf < 4; ++nf) {
                const int col = w * 64 + nf * 16 + n;
                const bf16x8 br = *(const bf16x8*)(Wihbf + (size_t)col * 256 + kidx);
                const bf16x8 bz = *(const bf16x8*)(Wihbf + (size_t)(256 + col) * 256 + kidx);
                const bf16x8 bn = *(const bf16x8*)(Wihbf + (size_t)(512 + col) * 256 + kidx);
                ai0[nf] = MFMA(au, br, ai0[nf], 0, 0, 0);
                ai1[nf] = MFMA(au, bz, ai1[nf], 0, 0, 0);
                ai2[nf] = MFMA(au, bn, ai2[nf], 0, 0, 0);
            }
        }
        f32x4 ah0[4], ah1[4], ah2[4];
#pragma unroll
        for (int nf = 0; nf < 4; ++nf) { ah0[nf] = fz; ah1[nf] = fz; ah2[nf] = fz; }
#pragma unroll
        for (int kk = 0; kk < 8; ++kk) {
            const bf16x8 ah_ = *(const bf16x8*)((char*)hA + n * 512 + ((kk * 64 + lg * 16) ^ ((n & 7) << 4)));
            const int kidx = kk * 32 + lg * 8;
#pragma unroll
            for (int nf = 0; nf < 4; ++nf) {
                const int col = w * 64 + nf * 16 + n;
                const bf16x8 cr = *(const bf16x8*)(Whhbf + (size_t)col * 256 + kidx);
                const bf16x8 cz = *(const bf16x8*)(Whhbf + (size_t)(256 + col) * 256 + kidx);
                const bf16x8 cn = *(const bf16x8*)(Whhbf + (size_t)(512 + col) * 256 + kidx);
                ah0[nf] = MFMA(ah_, cr, ah0[nf], 0, 0, 0);
                ah1[nf] = MFMA(ah_, cz, ah1[nf], 0, 0, 0);
                ah2[nf] = MFMA(ah_, cn, ah2[nf], 0, 0, 0);
            }
        }
#pragma unroll
        for (int nf = 0; nf < 4; ++nf) {
            const int col = w * 64 + nf * 16 + n;
            const float br_ = bih[col], bz_ = bih[256 + col], bn_ = bih[512 + col];
            const float cr_ = bhh[col], cz_ = bhh[256 + col], cn_ = bhh[512 + col];
#pragma unroll
            for (int r = 0; r < 4; ++r) {
                const int rowm = lg * 4 + r;
                const float ir = ai0[nf][r] + br_, iz = ai1[nf][r] + bz_, inn = ai2[nf][r] + bn_;
                const float hr = ah0[nf][r] + cr_, hz = ah1[nf][r] + cz_, hn = ah2[nf][r] + cn_;
                const float rg = 1.f / (1.f + __expf(-(ir + hr)));
                const float zg = 1.f / (1.f + __expf(-(iz + hz)));
                const float ng = tanhf(inn + rg * hn);
                const float h0v = hf32[rowm * 264 + col];
                sv[nf][r] = (1.f - zg) * ng + zg * h0v;
            }
        }
    }
    ln_rows(sv, (char*)uA, red, lnmw, lnmb, w, n, lg, w * 64 + n);
    __syncthreads();

    // ---- stage 3: MLP1
    {
        f32x4 m1[8];
#pragma unroll
        for (int nf = 0; nf < 8; ++nf) m1[nf] = fz;
#pragma unroll
        for (int kk = 0; kk < 8; ++kk) {
            const bf16x8 a = *(const bf16x8*)((char*)uA + n * 512 + ((kk * 64 + lg * 16) ^ ((n & 7) << 4)));
            const int kidx = kk * 32 + lg * 8;
#pragma unroll
            for (int nf = 0; nf < 8; ++nf) {
                const int colh = w * 128 + nf * 16 + n;
                const bf16x8 bb = *(const bf16x8*)(W1T + (size_t)colh * 256 + kidx);
                m1[nf] = MFMA(a, bb, m1[nf], 0, 0, 0);
            }
        }
        __syncthreads();
#pragma unroll
        for (int nf = 0; nf < 8; ++nf) {
            const int colh = w * 128 + nf * 16 + n;
            const float bb = b1[colh];
#pragma unroll
            for (int r = 0; r < 4; ++r) {
                const int rowm = lg * 4 + r;
                *(unsigned short*)(hidA + rowm * 1024 + ((colh * 2) ^ ((rowm & 7) << 4)))
                    = f2bf(fmaxf(m1[nf][r] + bb, 0.f));
            }
        }
    }
    __syncthreads();

    // ---- stage 4: MLP2 + residual
    {
        f32x4 m2[4];
#pragma unroll
        for (int nf = 0; nf < 4; ++nf) m2[nf] = fz;
#pragma unroll
        for (int kk = 0; kk < 16; ++kk) {
            const bf16x8 a = *(const bf16x8*)(hidA + n * 1024 + ((kk * 64 + lg * 16) ^ ((n & 7) << 4)));
            const int kidx = kk * 32 + lg * 8;
#pragma unroll
            for (int nf = 0; nf < 4; ++nf) {
                const int col = w * 64 + nf * 16 + n;
                const bf16x8 bb = *(const bf16x8*)(W2T + (size_t)col * 512 + kidx);
                m2[nf] = MFMA(a, bb, m2[nf], 0, 0, 0);
            }
        }
#pragma unroll
        for (int nf = 0; nf < 4; ++nf) {
            const int col = w * 64 + nf * 16 + n;
            const float bb = b2[col];
#pragma unroll
            for (int r = 0; r < 4; ++r) {
                const int rowm = lg * 4 + r;
                const float v = m2[nf][r] + bb + sv[nf][r];
                sv[nf][r] = v;
                slots[(size_t)(R0 + rowm) * 256 + col] = v;
            }
        }
    }
    ln_rows(sv, (char*)hA, red, lnsw, lnsb, w, n, lg, w * 64 + n);
    __syncthreads();

    // ---- stage 5: q projection
    {
        f32x4 qa[4];
#pragma unroll
        for (int nf = 0; nf < 4; ++nf) qa[nf] = fz;
#pragma unroll
        for (int kk = 0; kk < 8; ++kk) {
            const bf16x8 a = *(const bf16x8*)((char*)hA + n * 512 + ((kk * 64 + lg * 16) ^ ((n & 7) << 4)));
            const int kidx = kk * 32 + lg * 8;
#pragma unroll
            for (int nf = 0; nf < 4; ++nf) {
                const int col = w * 64 + nf * 16 + n;
                const bf16x8 bb = *(const bf16x8*)(WqT + (size_t)col * 256 + kidx);
                qa[nf] = MFMA(a, bb, qa[nf], 0, 0, 0);
            }
        }
#pragma unroll
        for (int nf = 0; nf < 4; ++nf) {
            const int col = w * 64 + nf * 16 + n;
#pragma unroll
            for (int r = 0; r < 4; ++r)
                qbuf[(size_t)(R0 + lg * 4 + r) * 256 + col] = qa[nf][r];
        }
    }
}

__global__ void k_den(const float* __restrict__ denp, float* __restrict__ invden)
{
    const int b = blockIdx.x, t = threadIdx.x;  // 32 threads
    float s = 0.f;
#pragma unroll
    for (int c = 0; c < NCH; ++c) s += denp[((size_t)b * NCH + c) * HQ + t];
    invden[b * HQ + t] = 1.f / (s + (float)KK * EPS);
}

__global__ void k7_copy(const float* __restrict__ s, float* __restrict__ o)
{
    const int i = blockIdx.x * 256 + threadIdx.x;
    o[i] = s[i];
}

__global__ __launch_bounds__(256) void k7_attnout(
    const float* __restrict__ pbuf, const float* __restrict__ invden, float* __restrict__ out2)
{
    const int blk = blockIdx.x;
    const int b = blk >> 4;
    const int kk0 = (blk & 15) * 256;
    __shared__ float ps[256][33];
    __shared__ float inv[32];
    const int t = threadIdx.x;
    const float* pp = pbuf + ((size_t)b * KK + kk0) * HQ;
    for (int i = 0; i < 32; ++i) {
        const int idx = i * 256 + t;
        ps[idx >> 5][idx & 31] = pp[idx];
    }
    if (t < 32) inv[t] = invden[b * HQ + t];
    __syncthreads();
    float* o = out2 + (size_t)b * Q * KK + kk0 + t;
#pragma unroll
    for (int q = 0; q < 8; ++q) {
        float v = 0.f;
#pragma unroll
        for (int hh = 0; hh < 4; ++hh)
            v += (ps[t][hh * 8 + q] + EPS) * inv[hh * 8 + q];
        o[(size_t)q * KK] = v * 0.25f;
    }
}

extern "C" void kernel_launch(void* const* d_in, const int* in_sizes, int n_in,
                              void* d_out, int out_size, void* d_ws, size_t ws_size,
                              hipStream_t stream)
{
    const float* inputs  = (const float*)d_in[0];
    const float* slots0  = (const float*)d_in[1];
    const float* Wq      = (const float*)d_in[2];
    const float* Wk      = (const float*)d_in[3];
    const float* Wv      = (const float*)d_in[4];
    const float* ln_in_w = (const float*)d_in[5];
    const float* ln_in_b = (const float*)d_in[6];
    const float* ln_s_w  = (const float*)d_in[7];
    const float* ln_s_b  = (const float*)d_in[8];
    const float* ln_m_w  = (const float*)d_in[9];
    const float* ln_m_b  = (const float*)d_in[10];
    const float* gWih    = (const float*)d_in[11];
    const float* gWhh    = (const float*)d_in[12];
    const float* gbih    = (const float*)d_in[13];
    const float* gbhh    = (const float*)d_in[14];
    const float* W1      = (const float*)d_in[15];
    const float* b1      = (const float*)d_in[16];
    const float* W2      = (const float*)d_in[17];
    const float* b2      = (const float*)d_in[18];

    char* p = (char*)d_ws;
    unsigned short* kpk   = (unsigned short*)p; p += (size_t)B * KK * D * 2;
    unsigned short* vpk   = (unsigned short*)p; p += (size_t)B * KK * D * 2;
    float* pbuf   = (float*)p; p += (size_t)B * KK * HQ * 4;
    float* updp   = (float*)p; p += (size_t)B * NCH * Q * D * 4;
    float* denp   = (float*)p; p += (size_t)B * NCH * HQ * 4;
    float* invden = (float*)p; p += (size_t)B * HQ * 4;
    float* qbuf   = (float*)p; p += (size_t)B * Q * D * 4;
    float* slots  = (float*)p; p += (size_t)B * Q * D * 4;
    unsigned short* WkvT  = (unsigned short*)p; p += (size_t)512 * 256 * 2;
    unsigned short* Wihbf = (unsigned short*)p; p += (size_t)768 * 256 * 2;
    unsigned short* Whhbf = (unsigned short*)p; p += (size_t)768 * 256 * 2;
    unsigned short* W1T   = (unsigned short*)p; p += (size_t)HM * 256 * 2;
    unsigned short* W2T   = (unsigned short*)p; p += (size_t)256 * HM * 2;
    unsigned short* WqT   = (unsigned short*)p; p += (size_t)256 * 256 * 2;

    k_prep<<<3584, 256, 0, stream>>>(Wk, Wv, gWih, gWhh, W1, W2, Wq, slots0,
                                     WkvT, Wihbf, Whhbf, W1T, W2T, WqT, slots);
    k1_mfma<<<(B * KK) / 64, 256, 0, stream>>>(inputs, WkvT, ln_in_w, ln_in_b, kpk, vpk);
    k2_qproj<<<B * Q, 256, 0, stream>>>(slots, Wq, ln_s_w, ln_s_b, qbuf);
    for (int it = 0; it < 3; ++it) {
        k_attn<<<B * NCH, 256, 0, stream>>>(kpk, vpk, qbuf, updp, denp, pbuf, (it == 2) ? 1 : 0);
        k_slot<<<32, 256, 0, stream>>>(updp, denp, slots, Wihbf, Whhbf, gbih, gbhh,
                                       W1T, b1, W2T, b2, ln_m_w, ln_m_b, WqT,
                                       ln_s_w, ln_s_b, qbuf);
    }
    k_den<<<B, 32, 0, stream>>>(denp, invden);
    k7_copy<<<(B * Q * D) / 256, 256, 0, stream>>>(slots, (float*)d_out);
    k7_attnout<<<B * (KK / 256), 256, 0, stream>>>(pbuf, invden, (float*)d_out + (size_t)B * Q * D);
}